// Round 8
// baseline (874.360 us; speedup 1.0000x reference)
//
#include <hip/hip_runtime.h>
#include <type_traits>

typedef unsigned long long u64;
typedef unsigned int u32;

#define BLOCK     256           // 4 waves
#define WAVES     4
#define TILE      4096          // items per scatter block
#define SUBT      1024          // items per wave (contiguous, stability)
#define CHUNKS    16            // SUBT/64 == TILE/BLOCK
#define KSHIFT    21
#define KBIAS     (1LL << 21)   // min key -1,787,119 > -2^21; max < 2^33
#define KMASK     ((1u << 21) - 1)
#define GRP       128

// Pass plan (33 key bits = 8+8+9+8, LSD, onesweep R12):
//  p1: u64 @21  p2: u64 @29  p3: u64->u32 shrink @37 (r512)  p4: u32 @21 -> dout
//  Unified per-sort digit space: [p1:0-255][p2:256-511][p3:512-1023][p4:1024-1279]
//
// Session ledger:
// R5: transposed hist + coalesced scanA; XCD swizzle in scatter. 394.6us.
// R6 (REVERTED): per-item fused-hist global atomics = memory-side RMW on gfx950
//     (cross-XCD): +317MB/scatter. NEVER per-item device atomics on the hot path.
// R7 (REVERTED): TILE 2048: occupancy 30->62% but scatter only -5% (not
//     latency-bound); doubled B slowed the rest.
// R8 (kept): flat2win folded into keygen; int32 hash3. 395.7us.
// R9 (REVERTED): radix 2048: 115us/scatter (LDS cap, serial 2048-scan, RL-2 writes).
// R10 (REVERTED): hist-hoist + setprio: scatter 50->55.
// R11 (REVERTED): keygen parity-split: neutral (keygen was <50us, not ~105).
// R12: ONESWEEP. allhist_k computes all 4 pass histograms in ONE sweep of the
//     unsorted keys (digit hists are order-invariant); reduce_k scans -> dbase.
//     scatter_k self-ranks + decoupled lookback (publish AGG/PREFIX per digit,
//     AGENT-scope atomics bypass non-coherent XCD L2s). Eliminates 3 hist_k +
//     4 scanA + gaps. Scatter swizzle REMOVED (lookback liveness requires
//     launch-order monotone chains; rocPRIM lookback relies on the same).

__device__ __forceinline__ void hash3(int x, int y, int z,
                                      long long boff, long long* v) {
  int x1 = x >> 4, y1 = y >> 4, z1 = z >> 3;
  int x2 = x & 15, y2 = y & 15, z2 = z & 7;
  int sx  = 1 - 2*(x1 & 1), sy  = 1 - 2*(y1 & 1), sz  = 1 - 2*(z1 & 1);
  int s2x = 1 - 2*(x2 & 1), s2y = 1 - 2*(y2 & 1), s2z = 1 - 2*(z2 & 1);
  v[0] = (long long)(99*y1 + 9801*z1 + sy*x1) * 55296
         + (sy*(48*x2 + 2304*z2 + s2x*y2)) + boff;
  v[1] = (long long)(99*z1 + 2673*x1 + sz*y1) * 55296
         + (sz*(24*y2 + 1152*x2 + s2y*z2)) + boff;
  v[2] = (long long)(27*x1 + 2673*y1 + sx*z1) * 55296
         + (sx*(48*z2 + 1152*y2 + s2z*x2)) + boff;
}

__global__ void count_k(const int* __restrict__ coords, unsigned* __restrict__ counts, int N) {
  __shared__ unsigned c[8];
  if (threadIdx.x < 8) c[threadIdx.x] = 0;
  __syncthreads();
  for (int i = blockIdx.x*blockDim.x + threadIdx.x; i < N; i += gridDim.x*blockDim.x)
    atomicAdd(&c[coords[4*i] & 7], 1u);
  __syncthreads();
  if (threadIdx.x < 8) atomicAdd(&counts[threadIdx.x], c[threadIdx.x]);
}

__global__ void prefix_k(const unsigned* __restrict__ counts, long long* __restrict__ meta,
                         const int* __restrict__ bsz) {
  int NB = *bsz; if (NB > 8) NB = 8;
  long long run_bs = 0, run_bsp = 0;
  meta[0] = 0;
  for (int b = 0; b < NB; b++) {
    long long c  = (long long)counts[b];
    long long cp = (c + GRP - 1) / GRP * GRP;
    long long r  = c % GRP;
    meta[9 + b]  = run_bsp - run_bs;
    meta[17 + b] = r ? (run_bsp + cp - GRP + r) : 0x7fffffffffffffffLL;
    run_bs += c; run_bsp += cp;
    meta[b + 1] = run_bsp;
  }
  meta[25] = run_bsp;
  meta[26] = NB;
}

// keygen: pure hash + key write + aux/flat2win (no hist under onesweep)
__global__ void __launch_bounds__(BLOCK) keygen_k(const int* __restrict__ coords,
                                                  u64* __restrict__ keys,
                                                  const long long* __restrict__ meta,
                                                  int* __restrict__ dout,
                                                  int N, int B, int g0, int g, int doAux) {
  int b = blockIdx.x, tid = threadIdx.x;
  long long Np = meta[25];
  for (int t = 0; t < CHUNKS; t++) {
    int i = b * TILE + t * BLOCK + tid;
    if (i < N) {
      int4 c4 = ((const int4*)coords)[i];
      long long boff = (long long)c4.x * 167772160LL;
      long long v[6];
      hash3(c4.y,     c4.z,     c4.w,     boff, v);
      hash3(c4.y + 8, c4.z + 8, c4.w + 4, boff, v + 3);
      #pragma unroll
      for (int s = 0; s < 6; s++) {
        if (s >= g0 && s < g0 + g) {
          u64 kb = (u64)(v[s] + KBIAS);
          keys[(size_t)(s - g0) * N + i] = (kb << KSHIFT) | (unsigned)i;
        }
      }
      if (doAux) dout[Np + i] = (int)(i + meta[9 + c4.x]);
    }
  }
  if (doAux) {                                    // folded flat2win (R8)
    int NB = (int)meta[26];
    for (int t = 0; t < CHUNKS; t++) {
      long long p = (long long)b * TILE + t * BLOCK + tid;
      if (p < Np) {
        int bb = 0;
        while (bb < NB - 1 && meta[bb + 1] <= p) bb++;
        long long pad = (p >= meta[17 + bb]) ? 1 : 0;
        dout[p] = (int)(p - GRP * pad - meta[9 + bb]);
      }
    }
    if (b == B - 1) {
      int NB2 = (int)meta[26];
      for (long long p = (long long)B * TILE + tid; p < Np; p += BLOCK) {
        int bb = 0;
        while (bb < NB2 - 1 && meta[bb + 1] <= p) bb++;
        long long pad = (p >= meta[17 + bb]) ? 1 : 0;
        dout[p] = (int)(p - GRP * pad - meta[9 + bb]);
      }
    }
  }
}

// ONE sweep of unsorted keys -> per-block hists for ALL 4 passes (order-invariant)
__global__ void __launch_bounds__(BLOCK) allhist_k(const u64* __restrict__ keys,
                                                   u32* __restrict__ hist, int N, int B) {
  __shared__ u32 cnt[1280];
  int s = blockIdx.y, b = blockIdx.x, tid = threadIdx.x;
  for (int j = tid; j < 1280; j += BLOCK) cnt[j] = 0;
  __syncthreads();
  const u64* in = keys + (size_t)s * N;
  #pragma unroll 4
  for (int t = 0; t < CHUNKS; t++) {
    int i = b * TILE + t * BLOCK + tid;
    if (i < N) {
      u64 k = in[i];
      atomicAdd(&cnt[(unsigned)(k >> 21) & 255], 1u);
      atomicAdd(&cnt[256 + ((unsigned)(k >> 29) & 255)], 1u);
      atomicAdd(&cnt[512 + ((unsigned)(k >> 37) & 511)], 1u);
      atomicAdd(&cnt[1024 + ((unsigned)(k >> 46) & 255)], 1u);
    }
  }
  __syncthreads();
  // transposed: [s][j][b]
  for (int j = tid; j < 1280; j += BLOCK) hist[((size_t)s * 1280 + j) * B + b] = cnt[j];
}

// sum per-block hists over b + exclusive scan per pass segment -> dbase[s][1280]
__global__ void __launch_bounds__(BLOCK) reduce_k(const u32* __restrict__ hist,
                                                  u32* __restrict__ dbase, int B) {
  __shared__ u32 tot[1280];
  int s = blockIdx.x, tid = threadIdx.x;
  for (int j = tid; j < 1280; j += BLOCK) {
    const u32* row = hist + ((size_t)s * 1280 + j) * B;
    u32 sum = 0;
    for (int b = 0; b < B; b++) sum += row[b];
    tot[j] = sum;
  }
  __syncthreads();
  // segments: [0,256) [256,512) [512,1024) [1024,1280) — one wave each
  int w = tid >> 6, lane = tid & 63;
  const int segb[5] = {0, 256, 512, 1024, 1280};
  int beg = segb[w], end = segb[w + 1];
  u32 run = 0;
  for (int c = beg; c < end; c += 64) {
    u32 v = tot[c + lane], x = v;
    #pragma unroll
    for (int off = 1; off < 64; off <<= 1) { u32 u = __shfl_up(x, off); if (lane >= off) x += u; }
    dbase[(size_t)s * 1280 + c + lane] = run + x - v;
    run += __shfl(x, 63);
  }
}

// onesweep scatter: self-rank + decoupled lookback.
// MODE 0: u64->u64   MODE 1: u64->u32 shrink   MODE 2: u32->int32 dout
// lb entry: [31:30] status (0 inv, 1 agg, 2 prefix), [29:0] count (N < 2^21).
template<int RB, int SHIFT, int MODE>
__global__ void __launch_bounds__(BLOCK) scatter_k(const void* __restrict__ srcv,
                                                   void* __restrict__ dstv,
                                                   const u32* __restrict__ dbase,
                                                   u32* __restrict__ lb,
                                                   int N, int B, int POFS,
                                                   int* __restrict__ dout,
                                                   const long long* __restrict__ meta, int g0) {
  constexpr int RADIXN = 1 << RB;
  constexpr int DPT = (RADIXN + BLOCK - 1) / BLOCK;
  using KT = typename std::conditional<MODE == 2, u32, u64>::type;
  using ST = typename std::conditional<MODE == 0, u64, u32>::type;
  __shared__ ST items[TILE];
  __shared__ unsigned short dig[MODE == 1 ? TILE : 64];
  __shared__ unsigned short cnt[WAVES][RADIXN];
  __shared__ int exf[RADIXN];
  __shared__ u32 gbl[RADIXN];
  // NO swizzle: lookback liveness requires tile order == launch order.
  int s = blockIdx.y, b = blockIdx.x;
  int tid = threadIdx.x;
  int wave = tid >> 6, lane = tid & 63;
  for (int j = tid; j < WAVES * RADIXN; j += BLOCK) ((unsigned short*)cnt)[j] = 0;
  __syncthreads();

  const KT* in = (const KT*)srcv + (size_t)s * N;
  int subbase = b * TILE + wave * SUBT;
  bool full = (subbase + SUBT <= N);
  KT k[CHUNKS]; u32 pd[CHUNKS];
  if (full) {
    #pragma unroll
    for (int t = 0; t < CHUNKS; t++) k[t] = in[subbase + t * 64 + lane];
    #pragma unroll
    for (int t = 0; t < CHUNKS; t++) {
      unsigned d = (unsigned)(k[t] >> SHIFT) & (RADIXN - 1);
      u64 m = ~0ull;
      #pragma unroll
      for (int bit = 0; bit < RB; bit++) {
        u64 bal = __ballot((d >> bit) & 1);
        m &= ((d >> bit) & 1) ? bal : ~bal;
      }
      unsigned rank = __builtin_amdgcn_mbcnt_hi((u32)(m >> 32),
                        __builtin_amdgcn_mbcnt_lo((u32)m, 0u));
      unsigned pbase = cnt[wave][d];              // lockstep: all read before leader writes
      pd[t] = d | ((pbase + rank) << RB);
      if (rank == 0) cnt[wave][d] = (unsigned short)(pbase + (unsigned)__popcll(m));
    }
  } else {
    #pragma unroll
    for (int t = 0; t < CHUNKS; t++) k[t] = in[min(subbase + t * 64 + lane, N - 1)];
    #pragma unroll
    for (int t = 0; t < CHUNKS; t++) {
      int i = subbase + t * 64 + lane;
      bool valid = i < N;
      unsigned d = (unsigned)(k[t] >> SHIFT) & (RADIXN - 1);
      u64 m = __ballot(valid);
      #pragma unroll
      for (int bit = 0; bit < RB; bit++) {
        u64 bal = __ballot(valid && ((d >> bit) & 1));
        m &= ((d >> bit) & 1) ? bal : ~bal;
      }
      unsigned rank = __builtin_amdgcn_mbcnt_hi((u32)(m >> 32),
                        __builtin_amdgcn_mbcnt_lo((u32)m, 0u));
      unsigned pbase = cnt[wave][d];
      pd[t] = d | ((pbase + rank) << RB);
      if (valid && rank == 0) cnt[wave][d] = (unsigned short)(pbase + (unsigned)__popcll(m));
    }
  }
  __syncthreads();

  // totals -> exf; publish AGG (PREFIX if b==0) immediately; stash wave counts
  u32 sc[DPT][3];
  #pragma unroll
  for (int q = 0; q < DPT; q++) {
    int d = q * BLOCK + tid;
    u32 a0 = cnt[0][d], a1 = cnt[1][d], a2 = cnt[2][d], a3 = cnt[3][d];
    sc[q][0] = a0; sc[q][1] = a1; sc[q][2] = a2;
    u32 tot = a0 + a1 + a2 + a3;
    exf[d] = (int)tot;
    __hip_atomic_store(&lb[((size_t)s * B + b) * RADIXN + d],
                       tot | ((b == 0 ? 2u : 1u) << 30),
                       __ATOMIC_RELAXED, __HIP_MEMORY_SCOPE_AGENT);
  }
  __syncthreads();
  if (wave == 0) {                                // wave0: block-local digit scan
    u32 run = 0;
    #pragma unroll
    for (int c = 0; c < (RADIXN + 63) / 64; c++) {
      int dd = c * 64 + lane;
      u32 v = (u32)exf[dd], x = v;
      for (int off = 1; off < 64; off <<= 1) { u32 u = __shfl_up(x, off); if (lane >= off) x += u; }
      exf[dd] = (int)(run + x - v);
      run += __shfl(x, 63);
    }
  } else {                                        // waves 1-3: decoupled lookback
    for (int d = tid - 64; d < RADIXN; d += 192) {
      u32 look = 0; int bb = b - 1;
      while (bb >= 0) {
        u32 v;
        do {
          v = __hip_atomic_load(&lb[((size_t)s * B + bb) * RADIXN + d],
                                __ATOMIC_RELAXED, __HIP_MEMORY_SCOPE_AGENT);
          if (!(v >> 30)) __builtin_amdgcn_s_sleep(1);
        } while (!(v >> 30));
        look += v & 0x3fffffffu;
        if ((v >> 30) == 2u) break;
        bb--;
      }
      gbl[d] = look;
      if (b > 0) {
        u32 t4 = (u32)cnt[0][d] + cnt[1][d] + cnt[2][d] + cnt[3][d];
        __hip_atomic_store(&lb[((size_t)s * B + b) * RADIXN + d],
                           (look + t4) | (2u << 30),
                           __ATOMIC_RELAXED, __HIP_MEMORY_SCOPE_AGENT);
      }
    }
  }
  __syncthreads();
  const u32* dbrow = dbase + (size_t)s * 1280 + POFS;
  #pragma unroll
  for (int q = 0; q < DPT; q++) {
    int d = q * BLOCK + tid;
    int e = exf[d];
    u32 gb = dbrow[d] + gbl[d];                   // global base + lookback prefix
    cnt[0][d] = (unsigned short)e;
    cnt[1][d] = (unsigned short)(e + sc[q][0]);
    cnt[2][d] = (unsigned short)(e + sc[q][0] + sc[q][1]);
    cnt[3][d] = (unsigned short)(e + sc[q][0] + sc[q][1] + sc[q][2]);
    exf[d] = (int)gb - e;
  }
  __syncthreads();

  #pragma unroll
  for (int t = 0; t < CHUNKS; t++) {
    int i = subbase + t * 64 + lane;
    if (i < N) {
      unsigned d = pd[t] & (RADIXN - 1);
      unsigned lr = pd[t] >> RB;
      unsigned pos = (unsigned)cnt[wave][d] + lr;
      if constexpr (MODE == 1) {
        items[pos] = (u32)(((k[t] >> 46) << 21) | ((u32)k[t] & KMASK));
        dig[pos] = (unsigned short)d;
      } else {
        items[pos] = (ST)k[t];
      }
    }
  }
  __syncthreads();

  int validCount = N - b * TILE; if (validCount > TILE) validCount = TILE;
  long long obase = 0;
  if (MODE == 2) obase = meta[25] + (long long)N * (1 + g0 + s);
  u64* out64 = (u64*)dstv + (size_t)s * N;
  u32* out32 = (u32*)dstv + (size_t)s * N;
  #pragma unroll 4
  for (int t = 0; t < CHUNKS; t++) {
    int j = t * BLOCK + tid;
    if (j < validCount) {
      ST kk = items[j];
      if constexpr (MODE == 0) {
        unsigned d = (unsigned)(kk >> SHIFT) & (RADIXN - 1);
        out64[exf[d] + j] = kk;
      } else if constexpr (MODE == 1) {
        unsigned d = dig[j];
        out32[exf[d] + j] = kk;
      } else {
        unsigned d = (unsigned)(kk >> SHIFT) & (RADIXN - 1);
        dout[obase + exf[d] + j] = (int)(kk & KMASK);
      }
    }
  }
}

extern "C" void kernel_launch(void* const* d_in, const int* in_sizes, int n_in,
                              void* d_out, int out_size, void* d_ws, size_t ws_size,
                              hipStream_t stream) {
  const int* coords = (const int*)d_in[0];
  const int* bsz    = (const int*)d_in[1];
  int N = in_sizes[0] / 4;
  int* dout = (int*)d_out;
  char* ws = (char*)d_ws;
  int B = (N + TILE - 1) / TILE;

  auto align256 = [](size_t x) { return (x + 255) & ~(size_t)255; };

  int g = 1;
  size_t offHist = 512, offDb = 0, offLb = 0, offA = 0, offB = 0, lbsz = 0;
  const int cands[4] = {6, 3, 2, 1};
  for (int ci = 0; ci < 4; ci++) {
    int cg = cands[ci];
    size_t oDb = offHist + (size_t)cg * 1280 * B * 4;
    size_t oLb = align256(oDb + (size_t)cg * 1280 * 4);
    size_t ls  = (size_t)cg * B * 1280 * 4;        // 256+256+512+256 digits
    size_t oA  = align256(oLb + ls);
    size_t oB2 = oA + (size_t)cg * N * 8;
    size_t need = oB2 + (size_t)cg * N * 8;
    if (need <= ws_size || cg == 1) {
      g = cg; offDb = oDb; offLb = oLb; lbsz = ls; offA = oA; offB = oB2;
      if (need <= ws_size) break;
    }
  }

  unsigned*  counts = (unsigned*)ws;
  long long* meta   = (long long*)(ws + 64);
  u32*       hist   = (u32*)(ws + offHist);
  u32*       dbase  = (u32*)(ws + offDb);
  u32*       lb0    = (u32*)(ws + offLb);
  u32*       lb1    = lb0 + (size_t)g * B * 256;
  u32*       lb2    = lb1 + (size_t)g * B * 256;
  u32*       lb3    = lb2 + (size_t)g * B * 512;
  u64*       keysA  = (u64*)(ws + offA);
  u64*       keysB  = (u64*)(ws + offB);

  hipMemsetAsync(ws, 0, 512, stream);
  count_k<<<1024, 256, 0, stream>>>(coords, counts, N);
  prefix_k<<<1, 1, 0, stream>>>(counts, meta, bsz);

  for (int g0 = 0; g0 < 6; g0 += g) {
    hipMemsetAsync(lb0, 0, lbsz, stream);          // lookback status -> INVALID
    keygen_k<<<B, BLOCK, 0, stream>>>(coords, keysA, meta, dout, N, B, g0, g, g0 == 0);
    allhist_k<<<dim3(B, g), BLOCK, 0, stream>>>(keysA, hist, N, B);
    reduce_k<<<g, BLOCK, 0, stream>>>(hist, dbase, B);
    // pass 1: u64 @21, A -> B
    scatter_k<8, 21, 0><<<dim3(B, g), BLOCK, 0, stream>>>(keysA, keysB, dbase, lb0, N, B, 0,
                                                          dout, meta, g0);
    // pass 2: u64 @29, B -> A
    scatter_k<8, 29, 0><<<dim3(B, g), BLOCK, 0, stream>>>(keysB, keysA, dbase, lb1, N, B, 256,
                                                          dout, meta, g0);
    // pass 3: u64 r512 @37, A -> B (u32 shrink)
    scatter_k<9, 37, 1><<<dim3(B, g), BLOCK, 0, stream>>>(keysA, keysB, dbase, lb2, N, B, 512,
                                                          dout, meta, g0);
    // pass 4: u32 @21, B(u32) -> dout
    scatter_k<8, 21, 2><<<dim3(B, g), BLOCK, 0, stream>>>(keysB, keysA, dbase, lb3, N, B, 1024,
                                                          dout, meta, g0);
  }
}